// Round 4
// baseline (117.870 us; speedup 1.0000x reference)
//
#include <hip/hip_runtime.h>

// CAPE skip-gram NS loss: gather + dot products, miss-path-bound.
// 16 lanes per batch element, float4/lane -> one load instr = 4 full 256B rows.
// R4: (a) non-temporal hints on read-once traffic (emb_in rows, indices,
// output stores) to keep the 256MB L3 dedicated to the hot emb_out table
// (2.88 uses/row); (b) negs indices loaded with ONE lane-parallel instr +
// shfl broadcast instead of 10 broadcast loads (26 -> 14 VMEM instrs/wave).

typedef float f32x4 __attribute__((ext_vector_type(4)));

__global__ __launch_bounds__(256) void CAPE_43525198578167_kernel(
    const float* __restrict__ emb_in,    // [POI, 64]
    const float* __restrict__ emb_out,   // [POI, 64]
    const int*   __restrict__ target,    // [B]
    const int*   __restrict__ context,   // [B]
    const int*   __restrict__ negs,      // [B, NS]
    float* __restrict__ target_loss,     // [B]
    float* __restrict__ neg_loss,        // [B, NS]
    int B)
{
    const int lane16 = threadIdx.x & 15;
    const int b = (int)(blockIdx.x * 16 + (threadIdx.x >> 4));
    if (b >= B) return;

    const f32x4* ein4  = reinterpret_cast<const f32x4*>(emb_in);
    const f32x4* eout4 = reinterpret_cast<const f32x4*>(emb_out);

    // ---- index loads: streaming, non-temporal ----
    const int t = __builtin_nontemporal_load(&target[b]);
    const int c = __builtin_nontemporal_load(&context[b]);
    // one lane-parallel load for the 10 neg indices of this element
    const int myidx = __builtin_nontemporal_load(
        &negs[b * 10 + (lane16 < 10 ? lane16 : 9)]);

    // ---- row loads: emb_in read-once (nt), emb_out hot (cacheable) ----
    const f32x4 ei = __builtin_nontemporal_load(&ein4[(size_t)t * 16 + lane16]);
    const f32x4 eo = eout4[(size_t)c * 16 + lane16];

    const int lanebase = (int)(threadIdx.x & 48);   // group base within wave
    f32x4 v[10];
    #pragma unroll
    for (int n = 0; n < 10; ++n) {
        const int idx = __shfl(myidx, lanebase | n); // broadcast within group
        v[n] = eout4[(size_t)idx * 16 + lane16];
    }

    // ---- consume ----
    float p = ei[0] * eo[0] + ei[1] * eo[1] + ei[2] * eo[2] + ei[3] * eo[3];
    p += __shfl_xor(p, 1);
    p += __shfl_xor(p, 2);
    p += __shfl_xor(p, 4);
    p += __shfl_xor(p, 8);
    if (lane16 == 0)
        __builtin_nontemporal_store(p, &target_loss[b]);

    float myq = 0.0f;
    #pragma unroll
    for (int n = 0; n < 10; ++n) {
        float s = ei[0] * v[n][0] + ei[1] * v[n][1] + ei[2] * v[n][2] + ei[3] * v[n][3];
        s += __shfl_xor(s, 1);
        s += __shfl_xor(s, 2);
        s += __shfl_xor(s, 4);
        s += __shfl_xor(s, 8);
        if (lane16 == n) myq = s;        // lane n keeps result for sample n
    }
    if (lane16 < 10)
        __builtin_nontemporal_store(-myq, &neg_loss[b * 10 + lane16]);
}

extern "C" void kernel_launch(void* const* d_in, const int* in_sizes, int n_in,
                              void* d_out, int out_size, void* d_ws, size_t ws_size,
                              hipStream_t stream) {
    const float* emb_in  = (const float*)d_in[0];
    const float* emb_out = (const float*)d_in[1];
    const int*   target  = (const int*)d_in[2];
    const int*   context = (const int*)d_in[3];
    const int*   negs    = (const int*)d_in[4];

    const int B = in_sizes[2];           // 262144

    float* out = (float*)d_out;
    float* target_loss = out;            // [B]
    float* neg_loss    = out + B;        // [B, NS]

    const int block = 256;               // 16 elements per block
    const int grid  = (B + 15) / 16;     // 16384 short blocks -> backfill
    CAPE_43525198578167_kernel<<<grid, block, 0, stream>>>(
        emb_in, emb_out, target, context, negs, target_loss, neg_loss, B);
}